// Round 9
// baseline (209.317 us; speedup 1.0000x reference)
//
#include <hip/hip_runtime.h>
#include <math.h>

#define NROWS 32768
#define NCODE 1024
#define AMB_CAP 8192
#define GAP_THRESH 1.5e-4f  // exact fp32 gap; emulation err ~1e-5, np-ref rounding ~2e-5

typedef __attribute__((ext_vector_type(8))) short bf16x8;   // 8 bf16 = 4 VGPRs
typedef __attribute__((ext_vector_type(4))) float f32x4;    // MFMA acc

__device__ __forceinline__ unsigned short bf16_rne(float f) {
    unsigned u = __float_as_uint(f);
    unsigned r = u + 0x7FFFu + ((u >> 16) & 1u);
    return (unsigned short)(r >> 16);
}

// ---------------------------------------------------------------------------
// prep: cn4 = ||c||^2+4, minK=+inf bits, zero counter/gsumsq/tickets,
// codebook -> frag-major split-bf16 of (-2c) (wsB). 16 blocks x 64 codes.
// ---------------------------------------------------------------------------
__global__ __launch_bounds__(64) void vq_prep(
    const float* __restrict__ cb, float* __restrict__ cn4,
    unsigned* __restrict__ minK, unsigned* __restrict__ counter,
    float* __restrict__ gsumsq, unsigned* __restrict__ ticket,
    unsigned* __restrict__ ticket2, unsigned short* __restrict__ wsB)
{
    int c = blockIdx.x * 64 + threadIdx.x;
    if (c == 0) { *counter = 0u; *gsumsq = 0.f; *ticket = 0u; *ticket2 = 0u; }
    float v[64];
    const float4* src = (const float4*)(cb + (size_t)c * 64);
    float s = 0.f;
    #pragma unroll
    for (int i = 0; i < 16; i++) {
        float4 t = src[i];
        v[i*4+0] = t.x; v[i*4+1] = t.y; v[i*4+2] = t.z; v[i*4+3] = t.w;
        s += t.x*t.x + t.y*t.y + t.z*t.z + t.w*t.w;
    }
    cn4[c] = s + 4.0f;
    minK[c] = 0x7F800000u;   // +inf bits (full dists >= 0 -> raw-bit order ok)
    int cc = c >> 6, ct = (c >> 4) & 3, cl = c & 15;
    #pragma unroll
    for (int q = 0; q < 4; q++) {
        int half = q & 1, lo = q >> 1;
        #pragma unroll
        for (int g = 0; g < 4; g++) {
            unsigned short u8[8] __attribute__((aligned(16)));
            #pragma unroll
            for (int j = 0; j < 8; j++) {
                float f = -2.0f * v[half*32 + g*8 + j];   // exact scale
                unsigned short h = bf16_rne(f);
                if (lo) h = bf16_rne(f - __uint_as_float((unsigned)h << 16));
                u8[j] = h;
            }
            size_t off = (size_t)cc * 8192 + ct * 2048 + q * 512 + (g * 16 + cl) * 8;
            *(uint4*)(wsB + off) = *(const uint4*)u8;
        }
    }
}

// ---------------------------------------------------------------------------
// main (r22): r20's tile loop VERBATIM (9 rounds establish 42-43us as this
// structure's empirical floor: LDS-staged==L2-direct==no-shfl==forced-asm-
// pipeline; occupancy/pipelining/shfl all falsified as limiters). The win
// this round is TIMELINE fat: vq_tail's launch + cold start (~13us). Fusion
// via device-scope ticket gate: all 512 blocks fence + increment ticket2;
// blocks >=64 exit immediately (=> gate is deadlock-free: only 64 blocks
// ever spin, all others progress unconditionally); blocks 0..63 spin until
// ticket2==512 then run the fp64 amb fixup + loss (grid-stride 64),
// with tail LDS overlaid on main's dead arrays via union (69KB max;
// 2 blocks/CU = 138KB <= 160KB).
// ---------------------------------------------------------------------------
struct MainS {
    float    cn4L[1024];
    unsigned scrE[1024];
    float    mD1[128], mD2[128];
    int      mI1[128];
    int      tokS[64];
    float    redS[8];
};
struct TailS {
    float    cbS[16384];   // 64 KB: 256 codes x 64 dims
    double   xs[64];
    double   bd[256];
    int      bi[256];
    unsigned lastS;
    float    redS2[8];
};

__global__ __launch_bounds__(512, 4) void vq_main(
    const float* __restrict__ x, const float* __restrict__ cb,
    const unsigned short* __restrict__ wsB, const float* __restrict__ cn4,
    float* __restrict__ out, unsigned* __restrict__ minK,
    unsigned* __restrict__ counter, int* __restrict__ amb,
    float* __restrict__ gsumsq, unsigned* __restrict__ ticket,
    unsigned* __restrict__ ticket2, float* __restrict__ out_loss)
{
    __shared__ __align__(16) union { MainS m; TailS t; } S;

    const int tid = threadIdx.x;
    const int lane = tid & 63;
    const int wi = tid >> 6;         // 0..7
    const int g = wi >> 1;           // row group 0..3 (16 rows each)
    const int h = wi & 1;            // code half: codes h*512 .. +511
    const int ln15 = lane & 15;
    const int q = lane >> 4;
    const int row0 = blockIdx.x * 64;

    // stage cn4 (1024 f32) + init scrE
    S.m.cn4L[tid]       = cn4[tid];
    S.m.cn4L[512 + tid] = cn4[512 + tid];
    S.m.scrE[tid]       = 0x7F800000u;
    S.m.scrE[512 + tid] = 0x7F800000u;

    // ---- A: 16 rows fp32 -> split-bf16 frags in regs; row norms via shfl ----
    bf16x8 Ah0, Ah1, Al0, Al1;
    float xnm4[4];
    {
        const float* xr = x + (size_t)(row0 + g*16 + ln15) * 64 + q * 8;
        float4 f0 = *(const float4*)xr;
        float4 f1 = *(const float4*)(xr + 4);
        float4 f2 = *(const float4*)(xr + 32);
        float4 f3 = *(const float4*)(xr + 36);
        float fa[8] = {f0.x,f0.y,f0.z,f0.w,f1.x,f1.y,f1.z,f1.w};
        float fb[8] = {f2.x,f2.y,f2.z,f2.w,f3.x,f3.y,f3.z,f3.w};
        unsigned short hh8[8] __attribute__((aligned(16)));
        unsigned short ll8[8] __attribute__((aligned(16)));
        unsigned short h28[8] __attribute__((aligned(16)));
        unsigned short l28[8] __attribute__((aligned(16)));
        float ss = 0.f;
        #pragma unroll
        for (int j = 0; j < 8; j++) {
            ss += fa[j]*fa[j] + fb[j]*fb[j];
            unsigned short hh = bf16_rne(fa[j]);
            hh8[j] = hh; ll8[j] = bf16_rne(fa[j] - __uint_as_float((unsigned)hh << 16));
            hh = bf16_rne(fb[j]);
            h28[j] = hh; l28[j] = bf16_rne(fb[j] - __uint_as_float((unsigned)hh << 16));
        }
        Ah0 = *(const bf16x8*)hh8; Al0 = *(const bf16x8*)ll8;
        Ah1 = *(const bf16x8*)h28; Al1 = *(const bf16x8*)l28;
        ss += __shfl_xor(ss, 16);
        ss += __shfl_xor(ss, 32);            // ||x_row(ln15)||^2
        #pragma unroll
        for (int r = 0; r < 4; r++)
            xnm4[r] = __shfl(ss, (q << 2) | r, 64) - 4.0f;  // xn(row q*4+r) - 4
    }
    __syncthreads();   // cn4L + scrE ready

    float d1[4], d2[4];
    int   i1[4];
    #pragma unroll
    for (int r = 0; r < 4; r++) { d1[r] = INFINITY; d2[r] = INFINITY; i1[r] = 0; }

    // ---- tile loop: 32 tiles of 16 codes, B straight from L2, no barriers ----
    const char* wsQ = (const char*)wsB + (size_t)h * 131072 + lane * 16;
    #pragma unroll 4
    for (int t = 0; t < 32; t++) {
        const char* tb = wsQ + t * 4096;
        bf16x8 Bh0 = *(const bf16x8*)(tb);
        bf16x8 Bh1 = *(const bf16x8*)(tb + 1024);
        bf16x8 Bl0 = *(const bf16x8*)(tb + 2048);
        bf16x8 Bl1 = *(const bf16x8*)(tb + 3072);
        const int kid = h*512 + t*16 + ln15;
        const float cn4v = S.m.cn4L[kid];       // per-column (code) bias
        f32x4 a0 = {cn4v, cn4v, cn4v, cn4v};
        // 6-product split emulation (hi.hi + hi.lo + lo.hi), B pre-scaled by -2:
        // acc = cn4 - 2*x.c
        a0 = __builtin_amdgcn_mfma_f32_16x16x32_bf16(Ah0, Bh0, a0, 0, 0, 0);
        a0 = __builtin_amdgcn_mfma_f32_16x16x32_bf16(Ah1, Bh1, a0, 0, 0, 0);
        a0 = __builtin_amdgcn_mfma_f32_16x16x32_bf16(Ah0, Bl0, a0, 0, 0, 0);
        a0 = __builtin_amdgcn_mfma_f32_16x16x32_bf16(Ah1, Bl1, a0, 0, 0, 0);
        a0 = __builtin_amdgcn_mfma_f32_16x16x32_bf16(Al0, Bh0, a0, 0, 0, 0);
        a0 = __builtin_amdgcn_mfma_f32_16x16x32_bf16(Al1, Bh1, a0, 0, 0, 0);
        float cm = INFINITY;
        #pragma unroll
        for (int r = 0; r < 4; r++) {
            float wv = a0[r];                   // row q*4+r, code kid
            d2[r] = fminf(fmaxf(wv, d1[r]), d2[r]);
            bool lt = wv < d1[r];
            i1[r] = lt ? kid : i1[r];
            d1[r] = fminf(wv, d1[r]);
            cm = fminf(cm, wv + xnm4[r]);       // full dist (entropy), lane's 4 rows
        }
        atomicMin(&S.m.scrE[kid], __float_as_uint(cm));   // fire-and-forget
    }

    // ---- butterfly exact top-2 merge across the 16 code-column lanes ----
    #pragma unroll
    for (int d = 1; d < 16; d <<= 1) {
        #pragma unroll
        for (int r = 0; r < 4; r++) {
            float od1 = __shfl_xor(d1[r], d);
            int   oi1 = __shfl_xor(i1[r], d);
            float od2 = __shfl_xor(d2[r], d);
            bool take = (od1 < d1[r]) || (od1 == d1[r] && oi1 < i1[r]);
            float loser = take ? d1[r] : od1;
            d2[r] = fminf(fminf(d2[r], od2), loser);
            d1[r] = take ? od1 : d1[r];
            i1[r] = take ? oi1 : i1[r];
        }
    }
    if (ln15 == 0) {
        #pragma unroll
        for (int r = 0; r < 4; r++) {
            int idx = (g*16 + q*4 + r) * 2 + h;
            S.m.mD1[idx] = d1[r]; S.m.mI1[idx] = i1[r]; S.m.mD2[idx] = d2[r];
        }
    }
    __syncthreads();   // per-half candidates staged; all scrE atomics done

    // ---- exact cross-half merge -> token + ambiguity (1 thread/row) ----
    if (tid < 64) {
        float a1 = S.m.mD1[tid*2],   b1 = S.m.mD1[tid*2+1];
        int   ai = S.m.mI1[tid*2],   bi = S.m.mI1[tid*2+1];
        float a2 = S.m.mD2[tid*2],   b2 = S.m.mD2[tid*2+1];
        bool ta = (a1 < b1) || (a1 == b1 && ai < bi);
        float D1 = ta ? a1 : b1;
        int   I1 = ta ? ai : bi;
        float D2 = ta ? fminf(a2, b1) : fminf(b2, a1);
        S.m.tokS[tid] = I1;
        if (D2 - D1 < GAP_THRESH) {
            unsigned idx = atomicAdd(counter, 1u);
            if (idx < AMB_CAP) { amb[2*idx] = row0 + tid; amb[2*idx+1] = I1; }
        }
    }

    // ---- entropy: filtered global atomicMin ----
    {
        unsigned u0 = S.m.scrE[tid];
        if (u0 < minK[tid]) atomicMin(&minK[tid], u0);          // race benign: monotone
        unsigned u1 = S.m.scrE[512 + tid];
        if (u1 < minK[512 + tid]) atomicMin(&minK[512 + tid], u1);
    }
    __syncthreads();   // tokS ready

    // ---- emb gather + sumsq (512 threads x 2 float4 = 64 rows x 16) ----
    {
        float acc2 = 0.f;
        #pragma unroll
        for (int uu = 0; uu < 2; uu++) {
            int u = uu*512 + tid;
            int row = u >> 4, c4 = u & 15;
            int tok = S.m.tokS[row];
            float4 c = ((const float4*)(cb + (size_t)tok*64))[c4];
            float4 xx = ((const float4*)(x + (size_t)(row0 + row)*64))[c4];
            ((float4*)(out + (size_t)(row0 + row)*64))[c4] = c;
            float dx = c.x-xx.x, dy = c.y-xx.y, dz = c.z-xx.z, dw = c.w-xx.w;
            acc2 += dx*dx + dy*dy + dz*dz + dw*dw;
        }
        #pragma unroll
        for (int o = 32; o > 0; o >>= 1) acc2 += __shfl_down(acc2, o);
        if (lane == 0) S.m.redS[wi] = acc2;
        __syncthreads();
        if (tid == 0) {
            float t = 0.f;
            #pragma unroll
            for (int w = 0; w < 8; w++) t += S.m.redS[w];
            atomicAdd(gsumsq, t);
        }
    }

    // ================= fused tail (replaces vq_tail dispatch) =================
    __syncthreads();
    __threadfence();                             // release amb/minK/gsumsq/out
    if (tid == 0) atomicAdd(ticket2, 1u);        // every block signals completion
    if (blockIdx.x >= 64) return;                // non-tail blocks exit (progress!)

    if (tid == 0) {                              // 64 spinners only: deadlock-free
        while (atomicAdd(ticket2, 0u) < 512u) __builtin_amdgcn_s_sleep(8);
    }
    __syncthreads();
    __threadfence();                             // acquire

    // ---- A: fp64 re-decision for ambiguous rows (cb staged in LDS) ----
    unsigned cnt = *counter; if (cnt > AMB_CAP) cnt = AMB_CAP;
    for (unsigned i = blockIdx.x; i < cnt; i += 64u) {
        int row = amb[2*i], oldk = amb[2*i+1];
        __syncthreads();
        if (tid < 64) S.t.xs[tid] = (double)x[(size_t)row*64 + tid];
        __syncthreads();
        double xn = 0.0;
        #pragma unroll 8
        for (int d = 0; d < 64; d++) xn += S.t.xs[d]*S.t.xs[d];
        double best = INFINITY; int bk = 1 << 30;
        for (int b = 0; b < 4; b++) {           // 256 codes per batch
            __syncthreads();                    // cbS free for reuse
            #pragma unroll
            for (int k = 0; k < 8; k++)         // 64 KB coalesced: 8 float4/thread
                ((float4*)S.t.cbS)[k*512 + tid] = ((const float4*)cb)[b*4096 + k*512 + tid];
            __syncthreads();
            if (tid < 256) {
                int kcode = b*256 + tid;
                const int t6 = tid & 63;
                double dot = 0.0, cn2 = 0.0;
                #pragma unroll 8
                for (int dd = 0; dd < 64; dd++) {
                    int d = (dd + t6) & 63;     // rotation: 2 lanes/bank (free)
                    double cv = (double)S.t.cbS[tid*64 + d];
                    dot = fma(S.t.xs[d], cv, dot);
                    cn2 = fma(cv, cv, cn2);
                }
                double dist = (xn - 2.0*dot) + cn2;
                if (dist < best || (dist == best && kcode < bk)) { best = dist; bk = kcode; }
            }
        }
        if (tid < 256) { S.t.bd[tid] = best; S.t.bi[tid] = bk; }
        __syncthreads();
        for (int s = 128; s > 0; s >>= 1) {
            if (tid < s) {
                double od = S.t.bd[tid+s]; int ok = S.t.bi[tid+s];
                if (od < S.t.bd[tid] || (od == S.t.bd[tid] && ok < S.t.bi[tid])) {
                    S.t.bd[tid] = od; S.t.bi[tid] = ok;
                }
            }
            __syncthreads();
        }
        int bestk = S.t.bi[0];
        if (bestk != oldk) {
            double part = 0.0;
            if (tid < 64) {
                float cn = cb[(size_t)bestk*64 + tid];
                float co = cb[(size_t)oldk*64 + tid];
                out[(size_t)row*64 + tid] = cn;
                double dn = (double)cn - S.t.xs[tid];
                double dl = (double)co - S.t.xs[tid];
                part = dn*dn - dl*dl;
            }
            __syncthreads();
            if (tid < 256) S.t.bd[tid] = part;
            __syncthreads();
            for (int s = 128; s > 0; s >>= 1) {
                if (tid < s) S.t.bd[tid] += S.t.bd[tid+s];
                __syncthreads();
            }
            if (tid == 0) atomicAdd(gsumsq, (float)S.t.bd[0]);
        }
    }

    // ---- B: last tail block assembles the loss ----
    __syncthreads();
    if (tid == 0) {
        __threadfence();
        S.t.lastS = (atomicAdd(ticket, 1u) == 63u) ? 1u : 0u;
    }
    __syncthreads();
    if (S.t.lastS) {
        __threadfence();
        float s = 0.f;
        if (tid < 256) {
            #pragma unroll
            for (int jj = 0; jj < 4; jj++)
                s += __uint_as_float(minK[jj*256 + tid]);   // raw bits of positive dists
        }
        #pragma unroll
        for (int o = 32; o > 0; o >>= 1) s += __shfl_down(s, o);
        if (lane == 0) S.t.redS2[wi] = s;
        __syncthreads();
        if (tid == 0) {
            float gs = atomicAdd(gsumsq, 0.0f);             // coherent device-scope read
            float tot = 0.f;
            #pragma unroll
            for (int w = 0; w < 8; w++) tot += S.t.redS2[w];
            out_loss[0] = 1.25f * (gs / 2097152.0f) + 0.1f * (tot / 1024.0f);
        }
    }
}

extern "C" void kernel_launch(void* const* d_in, const int* in_sizes, int n_in,
                              void* d_out, int out_size, void* d_ws, size_t ws_size,
                              hipStream_t stream) {
    const float* x  = (const float*)d_in[0];   // [32768, 64]
    const float* cb = (const float*)d_in[1];   // [1024, 64]
    float* out = (float*)d_out;                // [0,2097152): emb; [2097152]: loss

    char* ws = (char*)d_ws;
    unsigned*       counter = (unsigned*)ws;                    // @0
    float*          gsumsq  = (float*)(ws + 4);                 // @4
    unsigned*       ticket  = (unsigned*)(ws + 8);              // @8  (loss ticket)
    unsigned*       ticket2 = (unsigned*)(ws + 12);             // @12 (completion gate)
    float*          cn4     = (float*)(ws + 1024);              // 4 KB
    unsigned*       minK    = (unsigned*)(ws + 8192);           // 4 KB
    int*            amb     = (int*)(ws + 16384);               // 64 KB
    unsigned short* wsB     = (unsigned short*)(ws + 131072);   // 256 KB

    vq_prep<<<16,  64,  0, stream>>>(cb, cn4, minK, counter, gsumsq, ticket, ticket2, wsB);
    vq_main<<<512, 512, 0, stream>>>(x, cb, wsB, cn4, out, minK, counter, amb, gsumsq,
                                     ticket, ticket2, out + 2097152);
}

// Round 10
// 115.327 us; speedup vs baseline: 1.8150x; 1.8150x over previous
//
#include <hip/hip_runtime.h>
#include <math.h>

#define NROWS 32768
#define NCODE 1024
#define AMB_CAP 8192
#define GAP_THRESH 1.5e-4f  // exact fp32 gap; emulation err ~1e-5, np-ref rounding ~2e-5

typedef __attribute__((ext_vector_type(8))) short bf16x8;   // 8 bf16 = 4 VGPRs
typedef __attribute__((ext_vector_type(4))) float f32x4;    // MFMA acc

__device__ __forceinline__ unsigned short bf16_rne(float f) {
    unsigned u = __float_as_uint(f);
    unsigned r = u + 0x7FFFu + ((u >> 16) & 1u);
    return (unsigned short)(r >> 16);
}

// ---------------------------------------------------------------------------
// prep: cn4 = ||c||^2+4, minK=+inf bits, zero counter/gsumsq/ticket,
// codebook -> frag-major split-bf16 of (-2c) (wsB). 16 blocks x 64 codes.
// B pre-scaled by -2 (exact exponent shift, commutes with bf16 RNE split) so
// vq_main's MFMA chain computes cn4 - 2*x.c with acc initialized to cn4.
// ---------------------------------------------------------------------------
__global__ __launch_bounds__(64) void vq_prep(
    const float* __restrict__ cb, float* __restrict__ cn4,
    unsigned* __restrict__ minK, unsigned* __restrict__ counter,
    float* __restrict__ gsumsq, unsigned* __restrict__ ticket,
    unsigned short* __restrict__ wsB)
{
    int c = blockIdx.x * 64 + threadIdx.x;
    if (c == 0) { *counter = 0u; *gsumsq = 0.f; *ticket = 0u; }
    float v[64];
    const float4* src = (const float4*)(cb + (size_t)c * 64);
    float s = 0.f;
    #pragma unroll
    for (int i = 0; i < 16; i++) {
        float4 t = src[i];
        v[i*4+0] = t.x; v[i*4+1] = t.y; v[i*4+2] = t.z; v[i*4+3] = t.w;
        s += t.x*t.x + t.y*t.y + t.z*t.z + t.w*t.w;
    }
    cn4[c] = s + 4.0f;
    minK[c] = 0x7F800000u;   // +inf bits (full dists >= 0 -> raw-bit order ok)
    int cc = c >> 6, ct = (c >> 4) & 3, cl = c & 15;
    #pragma unroll
    for (int q = 0; q < 4; q++) {
        int half = q & 1, lo = q >> 1;
        #pragma unroll
        for (int g = 0; g < 4; g++) {
            unsigned short u8[8] __attribute__((aligned(16)));
            #pragma unroll
            for (int j = 0; j < 8; j++) {
                float f = -2.0f * v[half*32 + g*8 + j];   // exact scale
                unsigned short h = bf16_rne(f);
                if (lo) h = bf16_rne(f - __uint_as_float((unsigned)h << 16));
                u8[j] = h;
            }
            size_t off = (size_t)cc * 8192 + ct * 2048 + q * 512 + (g * 16 + cl) * 8;
            *(uint4*)(wsB + off) = *(const uint4*)u8;
        }
    }
}

// ---------------------------------------------------------------------------
// main (r23 = r20 verbatim): the session's proven floor structure. Ledger:
// r13 (LDS-staged) == r15 (L2-direct) == r20 (atomic entropy) == 42-43 us;
// r16 (2x occupancy) -20%; r17/r18/r19/r21 (prefetch via rings / named
// slots / waves_per_eu / inline-asm vmcnt) all collapsed by the allocator's
// 64-VGPR pinning or spilled; r22 (tail fusion w/ device gate) -85%.
// Conclusion: per-wave serial chain + 64-VGPR regime is this kernel's
// compiler-bound floor at HIP level. 512 blocks x 512 thr, 8 waves =
// 4 row-groups x 2 code-halves, wave = 16 rows x 512 codes = 32 tiles,
// B straight from L2 (wsB 256 KB resident), acc init = cn4[col],
// B pre-scaled by -2 -> wv = acc[r], per-lane fire-and-forget entropy
// atomicMin (4 contenders/address, off the dependent chain).
// ---------------------------------------------------------------------------
__global__ __launch_bounds__(512, 4) void vq_main(
    const float* __restrict__ x, const float* __restrict__ cb,
    const unsigned short* __restrict__ wsB, const float* __restrict__ cn4,
    float* __restrict__ out, unsigned* __restrict__ minK,
    unsigned* __restrict__ counter, int* __restrict__ amb,
    float* __restrict__ gsumsq)
{
    __shared__ float    cn4L[1024];
    __shared__ unsigned scrE[1024];        // per-block per-code min full dist (raw bits)
    __shared__ float mD1[128], mD2[128];   // [row 0..63][half 0..1]
    __shared__ int   mI1[128];
    __shared__ int   tokS[64];
    __shared__ float redS[8];

    const int tid = threadIdx.x;
    const int lane = tid & 63;
    const int wi = tid >> 6;         // 0..7
    const int g = wi >> 1;           // row group 0..3 (16 rows each)
    const int h = wi & 1;            // code half: codes h*512 .. +511
    const int ln15 = lane & 15;
    const int q = lane >> 4;
    const int row0 = blockIdx.x * 64;

    // stage cn4 (1024 f32) + init scrE
    cn4L[tid]       = cn4[tid];
    cn4L[512 + tid] = cn4[512 + tid];
    scrE[tid]       = 0x7F800000u;
    scrE[512 + tid] = 0x7F800000u;

    // ---- A: 16 rows fp32 -> split-bf16 frags in regs; row norms via shfl ----
    bf16x8 Ah0, Ah1, Al0, Al1;
    float xnm4[4];
    {
        const float* xr = x + (size_t)(row0 + g*16 + ln15) * 64 + q * 8;
        float4 f0 = *(const float4*)xr;
        float4 f1 = *(const float4*)(xr + 4);
        float4 f2 = *(const float4*)(xr + 32);
        float4 f3 = *(const float4*)(xr + 36);
        float fa[8] = {f0.x,f0.y,f0.z,f0.w,f1.x,f1.y,f1.z,f1.w};
        float fb[8] = {f2.x,f2.y,f2.z,f2.w,f3.x,f3.y,f3.z,f3.w};
        unsigned short hh8[8] __attribute__((aligned(16)));
        unsigned short ll8[8] __attribute__((aligned(16)));
        unsigned short h28[8] __attribute__((aligned(16)));
        unsigned short l28[8] __attribute__((aligned(16)));
        float ss = 0.f;
        #pragma unroll
        for (int j = 0; j < 8; j++) {
            ss += fa[j]*fa[j] + fb[j]*fb[j];
            unsigned short hh = bf16_rne(fa[j]);
            hh8[j] = hh; ll8[j] = bf16_rne(fa[j] - __uint_as_float((unsigned)hh << 16));
            hh = bf16_rne(fb[j]);
            h28[j] = hh; l28[j] = bf16_rne(fb[j] - __uint_as_float((unsigned)hh << 16));
        }
        Ah0 = *(const bf16x8*)hh8; Al0 = *(const bf16x8*)ll8;
        Ah1 = *(const bf16x8*)h28; Al1 = *(const bf16x8*)l28;
        ss += __shfl_xor(ss, 16);
        ss += __shfl_xor(ss, 32);            // ||x_row(ln15)||^2
        #pragma unroll
        for (int r = 0; r < 4; r++)
            xnm4[r] = __shfl(ss, (q << 2) | r, 64) - 4.0f;  // xn(row q*4+r) - 4
    }
    __syncthreads();   // cn4L + scrE ready; the only barrier before the epilogue

    float d1[4], d2[4];
    int   i1[4];
    #pragma unroll
    for (int r = 0; r < 4; r++) { d1[r] = INFINITY; d2[r] = INFINITY; i1[r] = 0; }

    // ---- tile loop: 32 tiles of 16 codes, B straight from L2, no barriers ----
    const char* wsQ = (const char*)wsB + (size_t)h * 131072 + lane * 16;
    #pragma unroll 4
    for (int t = 0; t < 32; t++) {
        const char* tb = wsQ + t * 4096;
        bf16x8 Bh0 = *(const bf16x8*)(tb);
        bf16x8 Bh1 = *(const bf16x8*)(tb + 1024);
        bf16x8 Bl0 = *(const bf16x8*)(tb + 2048);
        bf16x8 Bl1 = *(const bf16x8*)(tb + 3072);
        const int kid = h*512 + t*16 + ln15;
        const float cn4v = cn4L[kid];           // per-column (code) bias
        f32x4 a0 = {cn4v, cn4v, cn4v, cn4v};
        // 6-product split emulation (hi.hi + hi.lo + lo.hi), B pre-scaled by -2:
        // acc = cn4 - 2*x.c
        a0 = __builtin_amdgcn_mfma_f32_16x16x32_bf16(Ah0, Bh0, a0, 0, 0, 0);
        a0 = __builtin_amdgcn_mfma_f32_16x16x32_bf16(Ah1, Bh1, a0, 0, 0, 0);
        a0 = __builtin_amdgcn_mfma_f32_16x16x32_bf16(Ah0, Bl0, a0, 0, 0, 0);
        a0 = __builtin_amdgcn_mfma_f32_16x16x32_bf16(Ah1, Bl1, a0, 0, 0, 0);
        a0 = __builtin_amdgcn_mfma_f32_16x16x32_bf16(Al0, Bh0, a0, 0, 0, 0);
        a0 = __builtin_amdgcn_mfma_f32_16x16x32_bf16(Al1, Bh1, a0, 0, 0, 0);
        float cm = INFINITY;
        #pragma unroll
        for (int r = 0; r < 4; r++) {
            float wv = a0[r];                   // row q*4+r, code kid
            // exact top-2: d2' = min(max(wv,d1),d2) (med3); d1' = min(wv,d1)
            d2[r] = fminf(fmaxf(wv, d1[r]), d2[r]);
            bool lt = wv < d1[r];
            i1[r] = lt ? kid : i1[r];
            d1[r] = fminf(wv, d1[r]);
            cm = fminf(cm, wv + xnm4[r]);       // full dist (entropy), lane's 4 rows
        }
        // fire-and-forget: off the dependent chain (4 contenders/address)
        atomicMin(&scrE[kid], __float_as_uint(cm));
    }

    // ---- butterfly exact top-2 merge across the 16 code-column lanes ----
    #pragma unroll
    for (int d = 1; d < 16; d <<= 1) {
        #pragma unroll
        for (int r = 0; r < 4; r++) {
            float od1 = __shfl_xor(d1[r], d);
            int   oi1 = __shfl_xor(i1[r], d);
            float od2 = __shfl_xor(d2[r], d);
            bool take = (od1 < d1[r]) || (od1 == d1[r] && oi1 < i1[r]);
            float loser = take ? d1[r] : od1;
            d2[r] = fminf(fminf(d2[r], od2), loser);
            d1[r] = take ? od1 : d1[r];
            i1[r] = take ? oi1 : i1[r];
        }
    }
    if (ln15 == 0) {
        #pragma unroll
        for (int r = 0; r < 4; r++) {
            int idx = (g*16 + q*4 + r) * 2 + h;
            mD1[idx] = d1[r]; mI1[idx] = i1[r]; mD2[idx] = d2[r];
        }
    }
    __syncthreads();   // per-half candidates staged; all scrE atomics done

    // ---- exact cross-half merge -> token + ambiguity (1 thread/row) ----
    if (tid < 64) {
        float a1 = mD1[tid*2],   b1 = mD1[tid*2+1];
        int   ai = mI1[tid*2],   bi = mI1[tid*2+1];
        float a2 = mD2[tid*2],   b2 = mD2[tid*2+1];
        bool ta = (a1 < b1) || (a1 == b1 && ai < bi);
        float D1 = ta ? a1 : b1;
        int   I1 = ta ? ai : bi;
        float D2 = ta ? fminf(a2, b1) : fminf(b2, a1);
        tokS[tid] = I1;
        if (D2 - D1 < GAP_THRESH) {
            unsigned idx = atomicAdd(counter, 1u);
            if (idx < AMB_CAP) { amb[2*idx] = row0 + tid; amb[2*idx+1] = I1; }
        }
    }

    // ---- entropy: filtered global atomicMin ----
    {
        unsigned u0 = scrE[tid];
        if (u0 < minK[tid]) atomicMin(&minK[tid], u0);          // race benign: monotone
        unsigned u1 = scrE[512 + tid];
        if (u1 < minK[512 + tid]) atomicMin(&minK[512 + tid], u1);
    }
    __syncthreads();   // tokS ready

    // ---- emb gather + sumsq (512 threads x 2 float4 = 64 rows x 16) ----
    {
        float acc2 = 0.f;
        #pragma unroll
        for (int uu = 0; uu < 2; uu++) {
            int u = uu*512 + tid;
            int row = u >> 4, c4 = u & 15;
            int tok = tokS[row];
            float4 c = ((const float4*)(cb + (size_t)tok*64))[c4];
            float4 xx = ((const float4*)(x + (size_t)(row0 + row)*64))[c4];
            ((float4*)(out + (size_t)(row0 + row)*64))[c4] = c;
            float dx = c.x-xx.x, dy = c.y-xx.y, dz = c.z-xx.z, dw = c.w-xx.w;
            acc2 += dx*dx + dy*dy + dz*dz + dw*dw;
        }
        #pragma unroll
        for (int o = 32; o > 0; o >>= 1) acc2 += __shfl_down(acc2, o);
        if (lane == 0) redS[wi] = acc2;
        __syncthreads();
        if (tid == 0) {
            float t = 0.f;
            #pragma unroll
            for (int w = 0; w < 8; w++) t += redS[w];
            atomicAdd(gsumsq, t);
        }
    }
}

// ---------------------------------------------------------------------------
// tail (r23): 128 blocks (was 64) -- halves the serial grid-stride
// iterations per block over the ambiguous rows (the tail's dominant term);
// loss ticket target 127. Loop already uses gridDim.x. Otherwise unchanged:
// (A) fp64 re-decision with cb staged through LDS in 4 coalesced 64-KB
// batches; (B) last-ticket block sums minK + assembles loss.
// ---------------------------------------------------------------------------
__global__ __launch_bounds__(256) void vq_tail(
    const float* __restrict__ x, const float* __restrict__ cb,
    float* __restrict__ out, const unsigned* __restrict__ counter,
    const int* __restrict__ amb, float* __restrict__ gsumsq,
    unsigned* __restrict__ ticket, const unsigned* __restrict__ minK,
    float* __restrict__ out_loss)
{
    __shared__ __align__(16) float cbS[16384];   // 64 KB: 256 codes x 64 dims
    __shared__ double xs[64];
    __shared__ double bd[256];
    __shared__ int    bi[256];
    __shared__ unsigned lastS;
    __shared__ float redS[4];

    const int tid = threadIdx.x;

    // ---- A: fp64 re-decision for ambiguous rows (coalesced cb staging) ----
    unsigned cnt = *counter; if (cnt > AMB_CAP) cnt = AMB_CAP;
    for (unsigned i = blockIdx.x; i < cnt; i += gridDim.x) {
        int row = amb[2*i], oldk = amb[2*i+1];
        __syncthreads();
        if (tid < 64) xs[tid] = (double)x[(size_t)row*64 + tid];
        __syncthreads();
        double xn = 0.0;
        #pragma unroll 8
        for (int d = 0; d < 64; d++) xn += xs[d]*xs[d];
        double best = INFINITY; int bk = 1 << 30;
        for (int b = 0; b < 4; b++) {           // 256 codes per batch
            __syncthreads();                    // cbS free for reuse
            #pragma unroll
            for (int k = 0; k < 16; k++)        // 64 KB coalesced: 16 float4/thread
                ((float4*)cbS)[k*256 + tid] = ((const float4*)cb)[b*4096 + k*256 + tid];
            __syncthreads();
            int kcode = b*256 + tid;
            const int t6 = tid & 63;
            double dot = 0.0, cn2 = 0.0;
            #pragma unroll 8
            for (int dd = 0; dd < 64; dd++) {
                int d = (dd + t6) & 63;         // rotation: 2 lanes/bank (free)
                double cv = (double)cbS[tid*64 + d];
                dot = fma(xs[d], cv, dot);
                cn2 = fma(cv, cv, cn2);
            }
            double dist = (xn - 2.0*dot) + cn2;
            if (dist < best || (dist == best && kcode < bk)) { best = dist; bk = kcode; }
        }
        bd[tid] = best; bi[tid] = bk;
        __syncthreads();
        for (int s = 128; s > 0; s >>= 1) {
            if (tid < s) {
                double od = bd[tid+s]; int ok = bi[tid+s];
                if (od < bd[tid] || (od == bd[tid] && ok < bi[tid])) { bd[tid] = od; bi[tid] = ok; }
            }
            __syncthreads();
        }
        int bestk = bi[0];
        if (bestk != oldk) {
            double part = 0.0;
            if (tid < 64) {
                float cn = cb[(size_t)bestk*64 + tid];
                float co = cb[(size_t)oldk*64 + tid];
                out[(size_t)row*64 + tid] = cn;
                double dn = (double)cn - xs[tid];
                double dl = (double)co - xs[tid];
                part = dn*dn - dl*dl;
            }
            __syncthreads();
            bd[tid] = part;
            __syncthreads();
            for (int s = 128; s > 0; s >>= 1) {
                if (tid < s) bd[tid] += bd[tid+s];
                __syncthreads();
            }
            if (tid == 0) atomicAdd(gsumsq, (float)bd[0]);
        }
    }

    // ---- B: last block assembles the loss ----
    __syncthreads();
    if (tid == 0) {
        __threadfence();
        lastS = (atomicAdd(ticket, 1u) == 127u) ? 1u : 0u;
    }
    __syncthreads();
    if (lastS) {
        __threadfence();
        float s = 0.f;
        #pragma unroll
        for (int jj = 0; jj < 4; jj++)
            s += __uint_as_float(minK[jj*256 + tid]);   // raw bits of positive dists
        #pragma unroll
        for (int o = 32; o > 0; o >>= 1) s += __shfl_down(s, o);
        if ((tid & 63) == 0) redS[tid >> 6] = s;
        __syncthreads();
        if (tid == 0) {
            float gs = atomicAdd(gsumsq, 0.0f);         // coherent device-scope read
            float tot = redS[0] + redS[1] + redS[2] + redS[3];
            out_loss[0] = 1.25f * (gs / 2097152.0f) + 0.1f * (tot / 1024.0f);
        }
    }
}

extern "C" void kernel_launch(void* const* d_in, const int* in_sizes, int n_in,
                              void* d_out, int out_size, void* d_ws, size_t ws_size,
                              hipStream_t stream) {
    const float* x  = (const float*)d_in[0];   // [32768, 64]
    const float* cb = (const float*)d_in[1];   // [1024, 64]
    float* out = (float*)d_out;                // [0,2097152): emb; [2097152]: loss

    char* ws = (char*)d_ws;
    unsigned*       counter = (unsigned*)ws;                    // @0
    float*          gsumsq  = (float*)(ws + 4);                 // @4
    unsigned*       ticket  = (unsigned*)(ws + 8);              // @8
    float*          cn4     = (float*)(ws + 1024);              // 4 KB
    unsigned*       minK    = (unsigned*)(ws + 8192);           // 4 KB
    int*            amb     = (int*)(ws + 16384);               // 64 KB
    unsigned short* wsB     = (unsigned short*)(ws + 131072);   // 256 KB

    vq_prep<<<16,  64,  0, stream>>>(cb, cn4, minK, counter, gsumsq, ticket, wsB);
    vq_main<<<512, 512, 0, stream>>>(x, cb, wsB, cn4, out, minK, counter, amb, gsumsq);
    vq_tail<<<128, 256, 0, stream>>>(x, cb, out, counter, amb, gsumsq, ticket, minK,
                                     out + 2097152);
}